// Round 1
// baseline (273.391 us; speedup 1.0000x reference)
//
#include <hip/hip_runtime.h>
#include <math.h>

#define HW 512
#define NIMG 24              // 8*3 images per tensor
#define NB 362               // radial bins
#define PLANE (HW*HW)

// ws layout (float units):
#define OFF_MAG 0                      // [NIMG*NB] per-image per-bin mag sums
#define OFF_D   (NIMG*NB)              // [NIMG*NB] per-image per-bin d sums
#define OFF_CNT (2*NIMG*NB)            // [NB] int counts
#define OFF_PR  18432                  // 48 planes, real part (24 pred then 24 target)
#define OFF_PI  (OFF_PR + 48*PLANE)    // 48 planes, imag part
// total ws need: (18432 + 2*48*262144)*4 B ~= 96.1 MiB

// Exact floor of shifted radius: pixel (ky,kx) unshifted -> shifted coords
// sy=(ky+256)&511; dy=sy-255.5 (half-integer). r_int = floor(sqrt(dy^2+dx^2)).
__device__ __forceinline__ int rbin(int ky, int kx) {
    int sy = (ky + 256) & 511;
    int sx = (kx + 256) & 511;
    int py = 2*sy - 511;             // odd ints, 2*dy
    int px = 2*sx - 511;
    int m2 = py*py + px*px;          // <= 522242 < 2^24, exact in float
    int k = (int)(0.5f * sqrtf((float)m2));
    if ((2*(k+1))*(2*(k+1)) <= m2) ++k;          // exact correction
    if (k > 0 && (2*k)*(2*k) > m2) --k;
    return k;
}

__device__ __forceinline__ void build_tw(float* twr, float* twi, int tid, int nthr) {
    for (int j = tid; j < 256; j += nthr) {
        float th = (float)j * (-6.2831853071795864769f / 512.0f);
        float s, c;
        sincosf(th, &s, &c);
        twr[j] = c; twi[j] = s;      // W_512^j = exp(-2*pi*i*j/512)
    }
}

// 512-pt forward Stockham radix-2 FFT, one wave (64 lanes) per line.
// Input in (xr,xi) natural order; result lands in (yr,yi) natural order (9 stages, odd).
// Block-wide barriers: every wave in the block must call this together.
__device__ void fft512(float* xr, float* xi, float* yr, float* yi,
                       const float* twr, const float* twi, int lane) {
    float *sr = xr, *si = xi, *dr = yr, *di = yi;
    for (int st = 0; st < 9; ++st) {
        __syncthreads();
        #pragma unroll
        for (int j = 0; j < 4; ++j) {
            int i = lane + 64*j;               // butterfly id, 0..255
            int twIdx = (i >> st) << st;       // p * s
            float ar = sr[i],     ai = si[i];
            float br = sr[i+256], bi = si[i+256];
            float ur = ar - br, ui = ai - bi;
            float wr = twr[twIdx], wi = twi[twIdx];
            int d0 = i + twIdx;
            dr[d0] = ar + br;
            di[d0] = ai + bi;
            dr[d0 + (1 << st)] = ur*wr - ui*wi;
            di[d0 + (1 << st)] = ur*wi + ui*wr;
        }
        float* t;
        t = sr; sr = dr; dr = t;
        t = si; si = di; di = t;
    }
    __syncthreads();
}

// Bin populations (mirrors np.bincount of r_int). 64 blocks x 256 thr x 16 pix.
__global__ __launch_bounds__(256) void k_counts(int* __restrict__ counts) {
    __shared__ int cb[NB];
    int t = threadIdx.x;
    for (int j = t; j < NB; j += 256) cb[j] = 0;
    __syncthreads();
    int base = blockIdx.x * 4096;
    #pragma unroll
    for (int j = 0; j < 16; ++j) {
        int idx = base + t + j*256;
        atomicAdd(&cb[rbin(idx >> 9, idx & 511)], 1);
    }
    __syncthreads();
    for (int j = t; j < NB; j += 256) atomicAdd(&counts[j], cb[j]);
}

// Row FFT: 48 images x 512 rows, real input. Block = 256 thr = 4 waves = 4 rows.
__global__ __launch_bounds__(256) void k_rowfft(const float* __restrict__ pred,
                                                const float* __restrict__ tgt,
                                                float* __restrict__ ws) {
    __shared__ float bAr[4][512], bAi[4][512], bBr[4][512], bBi[4][512];
    __shared__ float twr[256], twi[256];
    int t = threadIdx.x, lane = t & 63, w = t >> 6;
    build_tw(twr, twi, t, 256);
    int b = blockIdx.x;              // 48*128 blocks
    int img = b >> 7;                // 0..47
    int r = ((b & 127) << 2) + w;    // row this wave handles
    const float* in = (img < NIMG ? pred + (size_t)img*PLANE
                                  : tgt + (size_t)(img - NIMG)*PLANE) + (size_t)r*HW;
    const float4* in4 = (const float4*)in;
    #pragma unroll
    for (int j = 0; j < 2; ++j) {
        float4 v = in4[lane + 64*j];
        int k = 4*(lane + 64*j);
        bAr[w][k] = v.x; bAr[w][k+1] = v.y; bAr[w][k+2] = v.z; bAr[w][k+3] = v.w;
        bAi[w][k] = 0.f; bAi[w][k+1] = 0.f; bAi[w][k+2] = 0.f; bAi[w][k+3] = 0.f;
    }
    fft512(bAr[w], bAi[w], bBr[w], bBi[w], twr, twi, lane);
    float* outR = ws + OFF_PR + (size_t)img*PLANE + (size_t)r*HW;
    float* outI = ws + OFF_PI + (size_t)img*PLANE + (size_t)r*HW;
    #pragma unroll
    for (int j = 0; j < 8; ++j) {
        int k = lane + 64*j;
        outR[k] = bBr[w][k];
        outI[k] = bBi[w][k];
    }
}

// Column FFT (pred + target) + per-pixel d/mag + radial binning.
// Block = 256 thr = 4 waves = 4 consecutive columns of one image.
// Column-group swizzle: blocks with the same blockIdx%8 (same XCD) get a
// contiguous 64-column range -> L2 line reuse for the strided slab loads.
__global__ __launch_bounds__(256) void k_colfft(const float* __restrict__ ws,
                                                float* __restrict__ gM,
                                                float* __restrict__ gD) {
    __shared__ float bAr[4][512], bAi[4][512], bBr[4][512], bBi[4][512];
    __shared__ float twr[256], twi[256];
    __shared__ float binM[NB], binD[NB];
    int t = threadIdx.x, lane = t & 63, w = t >> 6;
    build_tw(twr, twi, t, 256);
    for (int j = t; j < NB; j += 256) { binM[j] = 0.f; binD[j] = 0.f; }
    int b = blockIdx.x;                     // NIMG*128
    int img = b >> 7;
    int cgl = b & 127;
    int c0 = ((((cgl & 7) << 4) + (cgl >> 3)) << 2);   // 4-aligned column base
    const float* PR  = ws + OFF_PR;
    const float* PIm = ws + OFF_PI;

    // ---- pred columns ----
    {
        const float* baseR = PR  + (size_t)img*PLANE;
        const float* baseI = PIm + (size_t)img*PLANE;
        #pragma unroll
        for (int h = 0; h < 2; ++h) {
            int r = t + 256*h;
            float4 vr = *(const float4*)(baseR + (size_t)r*HW + c0);
            float4 vi = *(const float4*)(baseI + (size_t)r*HW + c0);
            bAr[0][r] = vr.x; bAr[1][r] = vr.y; bAr[2][r] = vr.z; bAr[3][r] = vr.w;
            bAi[0][r] = vi.x; bAi[1][r] = vi.y; bAi[2][r] = vi.z; bAi[3][r] = vi.w;
        }
    }
    fft512(bAr[w], bAi[w], bBr[w], bBi[w], twr, twi, lane);
    float prr[8], pri[8];
    #pragma unroll
    for (int j = 0; j < 8; ++j) {
        int r = lane + 64*j;
        prr[j] = bBr[w][r]; pri[j] = bBi[w][r];
    }
    __syncthreads();

    // ---- target columns ----
    {
        const float* baseR = PR  + (size_t)(NIMG + img)*PLANE;
        const float* baseI = PIm + (size_t)(NIMG + img)*PLANE;
        #pragma unroll
        for (int h = 0; h < 2; ++h) {
            int r = t + 256*h;
            float4 vr = *(const float4*)(baseR + (size_t)r*HW + c0);
            float4 vi = *(const float4*)(baseI + (size_t)r*HW + c0);
            bAr[0][r] = vr.x; bAr[1][r] = vr.y; bAr[2][r] = vr.z; bAr[3][r] = vr.w;
            bAi[0][r] = vi.x; bAi[1][r] = vi.y; bAi[2][r] = vi.z; bAi[3][r] = vi.w;
        }
    }
    fft512(bAr[w], bAi[w], bBr[w], bBi[w], twr, twi, lane);

    int kx = c0 + w;
    #pragma unroll
    for (int j = 0; j < 8; ++j) {
        int ky = lane + 64*j;
        float trr = bBr[w][ky], tri = bBi[w][ky];
        float sp = prr[j]*prr[j] + pri[j]*pri[j];
        float st_ = trr*trr + tri*tri;
        float diff = sp - st_;                       // |P|^2 - |T|^2
        float er = prr[j] + 1e-8f;                   // EPS on real part only
        float mag = 10.0f * logf(er*er + pri[j]*pri[j]);  // 20*ln(|comp|)
        int ri = rbin(ky, kx);
        atomicAdd(&binM[ri], mag);
        atomicAdd(&binD[ri], diff*diff);
    }
    __syncthreads();
    for (int j = t; j < NB; j += 256) {
        atomicAdd(&gM[img*NB + j], binM[j]);
        atomicAdd(&gD[img*NB + j], binD[j]);
    }
}

// Per-image: bin means -> min/max normalize (NaN-propagating like jnp) ->
// psd_ext weights -> weighted sum of per-bin d sums -> atomic into d_out.
__global__ __launch_bounds__(512) void k_final(const float* __restrict__ gM,
                                               const float* __restrict__ gD,
                                               const int* __restrict__ counts,
                                               float* __restrict__ out) {
    __shared__ float meanb[NB];
    __shared__ float rmin[512], rmax[512];
    __shared__ double sred[512];
    int t = threadIdx.x, img = blockIdx.x;
    for (int j = t; j < NB; j += 512)
        meanb[j] = gM[img*NB + j] / (float)counts[j];
    __syncthreads();
    // psd = bins 1..360 inclusive; NaN-propagating min/max (jnp semantics)
    float vmin = INFINITY, vmax = -INFINITY;
    if (t >= 1 && t <= 360) { vmin = meanb[t]; vmax = meanb[t]; }
    rmin[t] = vmin; rmax[t] = vmax;
    __syncthreads();
    for (int s = 256; s > 0; s >>= 1) {
        if (t < s) {
            float a = rmin[t], bb = rmin[t+s];
            rmin[t] = (a != a || bb != bb) ? __int_as_float(0x7fc00000) : fminf(a, bb);
            a = rmax[t]; bb = rmax[t+s];
            rmax[t] = (a != a || bb != bb) ? __int_as_float(0x7fc00000) : fmaxf(a, bb);
        }
        __syncthreads();
    }
    float pmin = rmin[0], pmax = rmax[0];
    double part = 0.0;
    for (int k = t; k < NB; k += 512) {
        float wgt;
        if (k == NB - 1) {
            wgt = 1.0f;                       // psd_ext[last] = 0 -> w = 1
        } else {
            int idx = (k == 0) ? 1 : k;       // psd_ext[0] duplicates psd[0] (bin 1)
            float e = (meanb[idx] - pmin) / (pmax - pmin);
            float wv = 1.0f - e;
            if (wv != wv) wv = 0.0f;          // nan -> 0
            wv = fminf(fmaxf(wv, 0.0f), 1.0f);
            wgt = wv;
        }
        part += (double)wgt * (double)gD[img*NB + k];
    }
    sred[t] = part;
    __syncthreads();
    for (int s = 256; s > 0; s >>= 1) {
        if (t < s) sred[t] += sred[t+s];
        __syncthreads();
    }
    if (t == 0) atomicAdd(out, (float)(sred[0] / 6291456.0));
}

extern "C" void kernel_launch(void* const* d_in, const int* in_sizes, int n_in,
                              void* d_out, int out_size, void* d_ws, size_t ws_size,
                              hipStream_t stream) {
    const float* pred = (const float*)d_in[0];
    const float* tgt  = (const float*)d_in[1];
    float* ws = (float*)d_ws;
    // zero bin accumulators + counts + output (ws/d_out are poisoned each call)
    hipMemsetAsync(d_ws, 0, (size_t)(2*NIMG*NB + NB) * sizeof(float), stream);
    hipMemsetAsync(d_out, 0, sizeof(float), stream);
    k_counts<<<64, 256, 0, stream>>>((int*)(ws + OFF_CNT));
    k_rowfft<<<48*128, 256, 0, stream>>>(pred, tgt, ws);
    k_colfft<<<NIMG*128, 256, 0, stream>>>(ws, ws + OFF_MAG, ws + OFF_D);
    k_final<<<NIMG, 512, 0, stream>>>(ws + OFF_MAG, ws + OFF_D,
                                      (const int*)(ws + OFF_CNT), (float*)d_out);
}

// Round 2
// 220.299 us; speedup vs baseline: 1.2410x; 1.2410x over previous
//
#include <hip/hip_runtime.h>
#include <math.h>

#define HW 512
#define NIMG 24              // 8*3 images per tensor
#define NB 362               // radial bins
#define PLANE (HW*HW)

// ws layout (float units):
#define OFF_MAG 0                      // [NIMG*NB] per-image per-bin mag sums
#define OFF_D   (NIMG*NB)              // [NIMG*NB] per-image per-bin d sums
#define OFF_CNT (2*NIMG*NB)            // [NB] int counts
#define OFF_PR  18432                  // 48 planes, real part (24 pred then 24 target)
#define OFF_PI  (OFF_PR + 48*PLANE)    // 48 planes, imag part

// Exact floor of shifted radius (see R1 derivation; integer-exact).
__device__ __forceinline__ int rbin(int ky, int kx) {
    int sy = (ky + 256) & 511;
    int sx = (kx + 256) & 511;
    int py = 2*sy - 511;
    int px = 2*sx - 511;
    int m2 = py*py + px*px;
    int k = (int)(0.5f * sqrtf((float)m2));
    if ((2*(k+1))*(2*(k+1)) <= m2) ++k;
    if (k > 0 && (2*k)*(2*k) > m2) --k;
    return k;
}

__device__ __forceinline__ void cmul(float& xr, float& xi, float wr, float wi) {
    float r = xr*wr - xi*wi;
    xi = xr*wi + xi*wr;
    xr = r;
}

// 8-point DFT in registers, natural-order in and out. W_8 = e^{-2pi i/8}.
__device__ __forceinline__ void dft8(float ar[8], float ai[8]) {
    const float C = 0.70710678118654752440f;
    // even samples (0,2,4,6) -> E[0..3]
    float t0r=ar[0]+ar[4], t0i=ai[0]+ai[4];
    float t1r=ar[0]-ar[4], t1i=ai[0]-ai[4];
    float t2r=ar[2]+ar[6], t2i=ai[2]+ai[6];
    float t3r=ar[2]-ar[6], t3i=ai[2]-ai[6];
    float E0r=t0r+t2r, E0i=t0i+t2i;
    float E2r=t0r-t2r, E2i=t0i-t2i;
    float E1r=t1r+t3i, E1i=t1i-t3r;     // t1 - i*t3
    float E3r=t1r-t3i, E3i=t1i+t3r;     // t1 + i*t3
    // odd samples (1,3,5,7) -> O[0..3]
    float u0r=ar[1]+ar[5], u0i=ai[1]+ai[5];
    float u1r=ar[1]-ar[5], u1i=ai[1]-ai[5];
    float u2r=ar[3]+ar[7], u2i=ai[3]+ai[7];
    float u3r=ar[3]-ar[7], u3i=ai[3]-ai[7];
    float O0r=u0r+u2r, O0i=u0i+u2i;
    float O2r=u0r-u2r, O2i=u0i-u2i;
    float O1r=u1r+u3i, O1i=u1i-u3r;
    float O3r=u1r-u3i, O3i=u1i+u3r;
    // W8^1*O1, W8^2*O2, W8^3*O3
    float W1r = C*(O1r+O1i), W1i = C*(O1i-O1r);
    float W2r = O2i,         W2i = -O2r;
    float W3r = C*(O3i-O3r), W3i = -C*(O3r+O3i);
    ar[0]=E0r+O0r; ai[0]=E0i+O0i;
    ar[4]=E0r-O0r; ai[4]=E0i-O0i;
    ar[1]=E1r+W1r; ai[1]=E1i+W1i;
    ar[5]=E1r-W1r; ai[5]=E1i-W1i;
    ar[2]=E2r+W2r; ai[2]=E2i+W2i;
    ar[6]=E2r-W2r; ai[6]=E2i-W2i;
    ar[3]=E3r+W3r; ai[3]=E3i+W3i;
    ar[7]=E3r-W3r; ai[7]=E3i-W3i;
}

// Multiply a[k] by W^k for k=1..7, W=(wr,wi), iterative powers.
__device__ __forceinline__ void twiddle7(float ar[8], float ai[8], float wr, float wi) {
    float pr = wr, pi = wi;
    cmul(ar[1], ai[1], pr, pi);
    #pragma unroll
    for (int k = 2; k < 8; ++k) {
        float nr = pr*wr - pi*wi;
        pi = pr*wi + pi*wr;
        pr = nr;
        cmul(ar[k], ai[k], pr, pi);
    }
}

// 512-pt FFT, one wave per line, 8 complex elems/thread in registers.
// In:  ar[j],ai[j] = x[64*j + lane]
// Out: ar[d],ai[d] = X[(lane>>3) + 8*(lane&7) + 64*d]
// Lr/Li: per-wave 544-float scratch. 4 internal __syncthreads (block-lockstep).
__device__ void fft512r(float ar[8], float ai[8], float* Lr, float* Li, int lane) {
    float s, c;
    dft8(ar, ai);
    sincosf((float)lane * (-6.28318530717958647692f/512.0f), &s, &c);
    twiddle7(ar, ai, c, s);
    __syncthreads();                       // prior users of L are done
    #pragma unroll
    for (int j = 0; j < 8; ++j) { Lr[j*68+lane] = ar[j]; Li[j*68+lane] = ai[j]; }
    __syncthreads();
    int k1 = lane >> 3, b = lane & 7;
    #pragma unroll
    for (int a = 0; a < 8; ++a) { ar[a] = Lr[k1*68+8*a+b]; ai[a] = Li[k1*68+8*a+b]; }
    dft8(ar, ai);
    sincosf((float)b * (-6.28318530717958647692f/64.0f), &s, &c);
    twiddle7(ar, ai, c, s);
    __syncthreads();
    #pragma unroll
    for (int cc = 0; cc < 8; ++cc) {
        int ad = k1*68 + 8*cc + ((b + cc) & 7);   // swizzle: 2-way banks both dirs
        Lr[ad] = ar[cc]; Li[ad] = ai[cc];
    }
    __syncthreads();
    #pragma unroll
    for (int bb = 0; bb < 8; ++bb) {
        int ad = k1*68 + 8*b + ((bb + b) & 7);
        ar[bb] = Lr[ad]; ai[bb] = Li[ad];
    }
    dft8(ar, ai);
}

// Bin populations (mirrors np.bincount of r_int).
__global__ __launch_bounds__(256) void k_counts(int* __restrict__ counts) {
    __shared__ int cb[NB];
    int t = threadIdx.x;
    for (int j = t; j < NB; j += 256) cb[j] = 0;
    __syncthreads();
    int base = blockIdx.x * 4096;
    #pragma unroll
    for (int j = 0; j < 16; ++j) {
        int idx = base + t + j*256;
        atomicAdd(&cb[rbin(idx >> 9, idx & 511)], 1);
    }
    __syncthreads();
    for (int j = t; j < NB; j += 256) atomicAdd(&counts[j], cb[j]);
}

// Row FFT: 48 images x 512 rows. Block = 4 waves = 4 rows.
__global__ __launch_bounds__(256) void k_rowfft(const float* __restrict__ pred,
                                                const float* __restrict__ tgt,
                                                float* __restrict__ ws) {
    __shared__ float ex[4][2][544];
    int t = threadIdx.x, lane = t & 63, w = t >> 6;
    int b = blockIdx.x;
    int img = b >> 7;
    int r = ((b & 127) << 2) + w;
    const float* in = (img < NIMG ? pred + (size_t)img*PLANE
                                  : tgt + (size_t)(img - NIMG)*PLANE) + (size_t)r*HW;
    float ar[8], ai[8];
    #pragma unroll
    for (int j = 0; j < 8; ++j) { ar[j] = in[64*j + lane]; ai[j] = 0.f; }
    fft512r(ar, ai, ex[w][0], ex[w][1], lane);
    float* outR = ws + OFF_PR + (size_t)img*PLANE + (size_t)r*HW;
    float* outI = ws + OFF_PI + (size_t)img*PLANE + (size_t)r*HW;
    #pragma unroll
    for (int d = 0; d < 8; ++d) {
        int k = (lane >> 3) + ((lane & 7) << 3) + (d << 6);
        outR[k] = ar[d];
        outI[k] = ai[d];
    }
}

// Column FFT (pred + target) + per-pixel d/mag + radial binning.
// Block = 4 waves = 4 consecutive columns of one image (XCD-swizzled groups).
__global__ __launch_bounds__(256) void k_colfft(const float* __restrict__ ws,
                                                float* __restrict__ gM,
                                                float* __restrict__ gD) {
    __shared__ float ex[4][2][544];
    __shared__ float binM[NB], binD[NB];
    int t = threadIdx.x, lane = t & 63, w = t >> 6;
    for (int j = t; j < NB; j += 256) { binM[j] = 0.f; binD[j] = 0.f; }
    int bI = blockIdx.x;
    int img = bI >> 7;
    int cgl = bI & 127;
    int c0 = ((((cgl & 7) << 4) + (cgl >> 3)) << 2);
    const float* PR  = ws + OFF_PR;
    const float* PIm = ws + OFF_PI;
    float ar[8], ai[8], Prr[8], Pri[8];

    // ---- pred ----
    {
        const float* baseR = PR  + (size_t)img*PLANE;
        const float* baseI = PIm + (size_t)img*PLANE;
        #pragma unroll
        for (int h = 0; h < 2; ++h) {
            int r = t + 256*h;
            float4 vr = *(const float4*)(baseR + (size_t)r*HW + c0);
            float4 vi = *(const float4*)(baseI + (size_t)r*HW + c0);
            ex[0][0][r]=vr.x; ex[1][0][r]=vr.y; ex[2][0][r]=vr.z; ex[3][0][r]=vr.w;
            ex[0][1][r]=vi.x; ex[1][1][r]=vi.y; ex[2][1][r]=vi.z; ex[3][1][r]=vi.w;
        }
    }
    __syncthreads();
    #pragma unroll
    for (int j = 0; j < 8; ++j) { ar[j] = ex[w][0][64*j+lane]; ai[j] = ex[w][1][64*j+lane]; }
    fft512r(ar, ai, ex[w][0], ex[w][1], lane);
    #pragma unroll
    for (int d = 0; d < 8; ++d) { Prr[d] = ar[d]; Pri[d] = ai[d]; }
    __syncthreads();                       // everyone's ex2 reads done

    // ---- target ----
    {
        const float* baseR = PR  + (size_t)(NIMG + img)*PLANE;
        const float* baseI = PIm + (size_t)(NIMG + img)*PLANE;
        #pragma unroll
        for (int h = 0; h < 2; ++h) {
            int r = t + 256*h;
            float4 vr = *(const float4*)(baseR + (size_t)r*HW + c0);
            float4 vi = *(const float4*)(baseI + (size_t)r*HW + c0);
            ex[0][0][r]=vr.x; ex[1][0][r]=vr.y; ex[2][0][r]=vr.z; ex[3][0][r]=vr.w;
            ex[0][1][r]=vi.x; ex[1][1][r]=vi.y; ex[2][1][r]=vi.z; ex[3][1][r]=vi.w;
        }
    }
    __syncthreads();
    #pragma unroll
    for (int j = 0; j < 8; ++j) { ar[j] = ex[w][0][64*j+lane]; ai[j] = ex[w][1][64*j+lane]; }
    fft512r(ar, ai, ex[w][0], ex[w][1], lane);

    int kx = c0 + w;
    #pragma unroll
    for (int d = 0; d < 8; ++d) {
        int ky = (lane >> 3) + ((lane & 7) << 3) + (d << 6);
        float sp = Prr[d]*Prr[d] + Pri[d]*Pri[d];
        float st_ = ar[d]*ar[d] + ai[d]*ai[d];
        float diff = sp - st_;
        float er = Prr[d] + 1e-8f;
        float mag = 10.0f * logf(er*er + Pri[d]*Pri[d]);
        int ri = rbin(ky, kx);
        atomicAdd(&binM[ri], mag);
        atomicAdd(&binD[ri], diff*diff);
    }
    __syncthreads();
    for (int j = t; j < NB; j += 256) {
        atomicAdd(&gM[img*NB + j], binM[j]);
        atomicAdd(&gD[img*NB + j], binD[j]);
    }
}

// Per-image: bin means -> NaN-propagating min/max -> weights -> weighted sum.
__global__ __launch_bounds__(512) void k_final(const float* __restrict__ gM,
                                               const float* __restrict__ gD,
                                               const int* __restrict__ counts,
                                               float* __restrict__ out) {
    __shared__ float meanb[NB];
    __shared__ float rmin[512], rmax[512];
    __shared__ double sred[512];
    int t = threadIdx.x, img = blockIdx.x;
    for (int j = t; j < NB; j += 512)
        meanb[j] = gM[img*NB + j] / (float)counts[j];
    __syncthreads();
    float vmin = INFINITY, vmax = -INFINITY;
    if (t >= 1 && t <= 360) { vmin = meanb[t]; vmax = meanb[t]; }
    rmin[t] = vmin; rmax[t] = vmax;
    __syncthreads();
    for (int s = 256; s > 0; s >>= 1) {
        if (t < s) {
            float a = rmin[t], bb = rmin[t+s];
            rmin[t] = (a != a || bb != bb) ? __int_as_float(0x7fc00000) : fminf(a, bb);
            a = rmax[t]; bb = rmax[t+s];
            rmax[t] = (a != a || bb != bb) ? __int_as_float(0x7fc00000) : fmaxf(a, bb);
        }
        __syncthreads();
    }
    float pmin = rmin[0], pmax = rmax[0];
    double part = 0.0;
    for (int k = t; k < NB; k += 512) {
        float wgt;
        if (k == NB - 1) {
            wgt = 1.0f;
        } else {
            int idx = (k == 0) ? 1 : k;
            float e = (meanb[idx] - pmin) / (pmax - pmin);
            float wv = 1.0f - e;
            if (wv != wv) wv = 0.0f;
            wv = fminf(fmaxf(wv, 0.0f), 1.0f);
            wgt = wv;
        }
        part += (double)wgt * (double)gD[img*NB + k];
    }
    sred[t] = part;
    __syncthreads();
    for (int s = 256; s > 0; s >>= 1) {
        if (t < s) sred[t] += sred[t+s];
        __syncthreads();
    }
    if (t == 0) atomicAdd(out, (float)(sred[0] / 6291456.0));
}

extern "C" void kernel_launch(void* const* d_in, const int* in_sizes, int n_in,
                              void* d_out, int out_size, void* d_ws, size_t ws_size,
                              hipStream_t stream) {
    const float* pred = (const float*)d_in[0];
    const float* tgt  = (const float*)d_in[1];
    float* ws = (float*)d_ws;
    hipMemsetAsync(d_ws, 0, (size_t)(2*NIMG*NB + NB) * sizeof(float), stream);
    hipMemsetAsync(d_out, 0, sizeof(float), stream);
    k_counts<<<64, 256, 0, stream>>>((int*)(ws + OFF_CNT));
    k_rowfft<<<48*128, 256, 0, stream>>>(pred, tgt, ws);
    k_colfft<<<NIMG*128, 256, 0, stream>>>(ws, ws + OFF_MAG, ws + OFF_D);
    k_final<<<NIMG, 512, 0, stream>>>(ws + OFF_MAG, ws + OFF_D,
                                      (const int*)(ws + OFF_CNT), (float*)d_out);
}

// Round 3
// 213.277 us; speedup vs baseline: 1.2819x; 1.0329x over previous
//
#include <hip/hip_runtime.h>
#include <math.h>

#define HW 512
#define NIMG 24              // 8*3 images per tensor
#define NB 362               // radial bins
#define PLANE (HW*HW)
#define NCG 32               // col-groups per image in k_colfft (16 cols each)

// ws layout (float units):
#define OFF_PM  0                          // [24*NCG*NB] partial mag sums
#define OFF_PD  (24*NCG*NB)                // [24*NCG*NB] partial d sums
#define OFF_CNT (2*24*NCG*NB)              // [NB] int counts
#define OFF_PR  557056                     // 48 planes, real, COL-MAJOR [col][row]
#define OFF_PI  (OFF_PR + 48*PLANE)        // 48 planes, imag, COL-MAJOR
// total: (557056 + 96*262144)*4 B = 98.1 MiB

// Exact floor of shifted radius (integer-exact; validated R1/R2).
__device__ __forceinline__ int rbin(int ky, int kx) {
    int sy = (ky + 256) & 511;
    int sx = (kx + 256) & 511;
    int py = 2*sy - 511;
    int px = 2*sx - 511;
    int m2 = py*py + px*px;
    int k = (int)(0.5f * sqrtf((float)m2));
    if ((2*(k+1))*(2*(k+1)) <= m2) ++k;
    if (k > 0 && (2*k)*(2*k) > m2) --k;
    return k;
}

__device__ __forceinline__ void cmul(float& xr, float& xi, float wr, float wi) {
    float r = xr*wr - xi*wi;
    xi = xr*wi + xi*wr;
    xr = r;
}

// 8-point DFT in registers, natural order (validated R2).
__device__ __forceinline__ void dft8(float ar[8], float ai[8]) {
    const float C = 0.70710678118654752440f;
    float t0r=ar[0]+ar[4], t0i=ai[0]+ai[4];
    float t1r=ar[0]-ar[4], t1i=ai[0]-ai[4];
    float t2r=ar[2]+ar[6], t2i=ai[2]+ai[6];
    float t3r=ar[2]-ar[6], t3i=ai[2]-ai[6];
    float E0r=t0r+t2r, E0i=t0i+t2i;
    float E2r=t0r-t2r, E2i=t0i-t2i;
    float E1r=t1r+t3i, E1i=t1i-t3r;
    float E3r=t1r-t3i, E3i=t1i+t3r;
    float u0r=ar[1]+ar[5], u0i=ai[1]+ai[5];
    float u1r=ar[1]-ar[5], u1i=ai[1]-ai[5];
    float u2r=ar[3]+ar[7], u2i=ai[3]+ai[7];
    float u3r=ar[3]-ar[7], u3i=ai[3]-ai[7];
    float O0r=u0r+u2r, O0i=u0i+u2i;
    float O2r=u0r-u2r, O2i=u0i-u2i;
    float O1r=u1r+u3i, O1i=u1i-u3r;
    float O3r=u1r-u3i, O3i=u1i+u3r;
    float W1r = C*(O1r+O1i), W1i = C*(O1i-O1r);
    float W2r = O2i,         W2i = -O2r;
    float W3r = C*(O3i-O3r), W3i = -C*(O3r+O3i);
    ar[0]=E0r+O0r; ai[0]=E0i+O0i;
    ar[4]=E0r-O0r; ai[4]=E0i-O0i;
    ar[1]=E1r+W1r; ai[1]=E1i+W1i;
    ar[5]=E1r-W1r; ai[5]=E1i-W1i;
    ar[2]=E2r+W2r; ai[2]=E2i+W2i;
    ar[6]=E2r-W2r; ai[6]=E2i-W2i;
    ar[3]=E3r+W3r; ai[3]=E3i+W3i;
    ar[7]=E3r-W3r; ai[7]=E3i-W3i;
}

__device__ __forceinline__ void twiddle7(float ar[8], float ai[8], float wr, float wi) {
    float pr = wr, pi = wi;
    cmul(ar[1], ai[1], pr, pi);
    #pragma unroll
    for (int k = 2; k < 8; ++k) {
        float nr = pr*wr - pi*wi;
        pi = pr*wi + pi*wr;
        pr = nr;
        cmul(ar[k], ai[k], pr, pi);
    }
}

// 512-pt FFT, one wave per line, PER-WAVE scratch (Lr/Li: 544 floats each).
// NO block barriers — wave-lockstep LDS exchange with wave_barrier fences.
// In:  ar[j] = x[64*j + lane];  Out: ar[d] = X[(lane>>3) + 8*(lane&7) + 64*d]
__device__ __forceinline__ void fft512r(float ar[8], float ai[8],
                                        float* Lr, float* Li, int lane) {
    float s, c;
    dft8(ar, ai);
    __sincosf((float)lane * (-6.28318530717958647692f/512.0f), &s, &c);
    twiddle7(ar, ai, c, s);
    __builtin_amdgcn_wave_barrier();
    #pragma unroll
    for (int j = 0; j < 8; ++j) { Lr[j*68+lane] = ar[j]; Li[j*68+lane] = ai[j]; }
    __builtin_amdgcn_wave_barrier();
    int k1 = lane >> 3, b = lane & 7;
    #pragma unroll
    for (int a = 0; a < 8; ++a) { ar[a] = Lr[k1*68+8*a+b]; ai[a] = Li[k1*68+8*a+b]; }
    dft8(ar, ai);
    __sincosf((float)b * (-6.28318530717958647692f/64.0f), &s, &c);
    twiddle7(ar, ai, c, s);
    __builtin_amdgcn_wave_barrier();
    #pragma unroll
    for (int cc = 0; cc < 8; ++cc) {
        int ad = k1*68 + 8*cc + ((b + cc) & 7);
        Lr[ad] = ar[cc]; Li[ad] = ai[cc];
    }
    __builtin_amdgcn_wave_barrier();
    #pragma unroll
    for (int bb = 0; bb < 8; ++bb) {
        int ad = k1*68 + 8*b + ((bb + b) & 7);
        ar[bb] = Lr[ad]; ai[bb] = Li[ad];
    }
    __builtin_amdgcn_wave_barrier();
    dft8(ar, ai);
}

// Bin populations (mirrors np.bincount of r_int).
__global__ __launch_bounds__(256) void k_counts(int* __restrict__ counts) {
    __shared__ int cb[NB];
    int t = threadIdx.x;
    for (int j = t; j < NB; j += 256) cb[j] = 0;
    __syncthreads();
    int base = blockIdx.x * 4096;
    #pragma unroll
    for (int j = 0; j < 16; ++j) {
        int idx = base + t + j*256;
        atomicAdd(&cb[rbin(idx >> 9, idx & 511)], 1);
    }
    __syncthreads();
    for (int j = t; j < NB; j += 256) atomicAdd(&counts[j], cb[j]);
}

// Row FFT + transposed write. Block = 16 waves = 16 rows of one plane.
// Output planes are COL-MAJOR: plane[col*512 + row]; each thread stores a
// 64B contiguous run (16 rows of one col), threads 0-511 do R, 512-1023 do I.
__global__ __launch_bounds__(1024) void k_rowfft(const float* __restrict__ pred,
                                                 const float* __restrict__ tgt,
                                                 float* __restrict__ ws) {
    __shared__ float smem[17408];          // 16 waves x 1088 scratch, aliased by T
    int t = threadIdx.x, lane = t & 63, w = t >> 6;
    int b = blockIdx.x;                    // 48*32
    int plane = b >> 5;
    int r0 = (b & 31) << 4;
    const float* in = (plane < NIMG ? pred + (size_t)plane*PLANE
                                    : tgt + (size_t)(plane - NIMG)*PLANE)
                      + (size_t)(r0 + w)*HW;
    float ar[8], ai[8];
    #pragma unroll
    for (int j = 0; j < 8; ++j) { ar[j] = in[64*j + lane]; ai[j] = 0.f; }
    float* Lr = smem + w*1088;
    fft512r(ar, ai, Lr, Lr + 544, lane);
    __syncthreads();                       // all scratch reads done before T writes
    // T tiles (alias scratch): TR[col*17 + w], TI at +8704
    float* TR = smem;
    float* TI = smem + 8704;
    #pragma unroll
    for (int d = 0; d < 8; ++d) {
        int k = (lane >> 3) + ((lane & 7) << 3) + (d << 6);
        TR[k*17 + w] = ar[d];
        TI[k*17 + w] = ai[d];
    }
    __syncthreads();
    int col = t & 511;
    const float* T = (t < 512) ? TR : TI;
    float* outP = ws + (size_t)((t < 512) ? OFF_PR : OFF_PI)
                  + (size_t)plane*PLANE + (size_t)col*HW + r0;
    float v[16];
    #pragma unroll
    for (int j = 0; j < 16; ++j) v[j] = T[col*17 + j];
    #pragma unroll
    for (int q = 0; q < 4; ++q)
        *(float4*)(outP + 4*q) = make_float4(v[4*q], v[4*q+1], v[4*q+2], v[4*q+3]);
}

// Column FFT (pred + target) + per-pixel d/mag + radial binning.
// Block = 16 waves, wave w owns col c0+w; col data is CONTIGUOUS (2KB runs).
// Partial bin sums written per block (no global atomics).
__global__ __launch_bounds__(1024) void k_colfft(const float* __restrict__ ws,
                                                 float* __restrict__ gPM,
                                                 float* __restrict__ gPD) {
    __shared__ float smem[17408];          // per-wave FFT scratch
    __shared__ float binM[NB], binD[NB];
    int t = threadIdx.x, lane = t & 63, w = t >> 6;
    for (int j = t; j < NB; j += 1024) { binM[j] = 0.f; binD[j] = 0.f; }
    __syncthreads();
    int b = blockIdx.x;                    // 24*NCG
    int img = b >> 5;
    int c = ((b & 31) << 4) + w;           // this wave's column
    float* Lr = smem + w*1088;
    float ar[8], ai[8], Prr[8], Pri[8];

    // ---- pred ----
    {
        const float* cR = ws + OFF_PR + (size_t)img*PLANE + (size_t)c*HW;
        const float* cI = ws + OFF_PI + (size_t)img*PLANE + (size_t)c*HW;
        #pragma unroll
        for (int j = 0; j < 8; ++j) { ar[j] = cR[64*j + lane]; ai[j] = cI[64*j + lane]; }
    }
    fft512r(ar, ai, Lr, Lr + 544, lane);
    #pragma unroll
    for (int d = 0; d < 8; ++d) { Prr[d] = ar[d]; Pri[d] = ai[d]; }

    // ---- target ----
    {
        const float* cR = ws + OFF_PR + (size_t)(NIMG + img)*PLANE + (size_t)c*HW;
        const float* cI = ws + OFF_PI + (size_t)(NIMG + img)*PLANE + (size_t)c*HW;
        #pragma unroll
        for (int j = 0; j < 8; ++j) { ar[j] = cR[64*j + lane]; ai[j] = cI[64*j + lane]; }
    }
    fft512r(ar, ai, Lr, Lr + 544, lane);

    #pragma unroll
    for (int d = 0; d < 8; ++d) {
        int ky = (lane >> 3) + ((lane & 7) << 3) + (d << 6);
        float sp = Prr[d]*Prr[d] + Pri[d]*Pri[d];
        float st_ = ar[d]*ar[d] + ai[d]*ai[d];
        float diff = sp - st_;
        float er = Prr[d] + 1e-8f;
        float mag = 10.0f * logf(er*er + Pri[d]*Pri[d]);
        int ri = rbin(ky, c);
        atomicAdd(&binM[ri], mag);
        atomicAdd(&binD[ri], diff*diff);
    }
    __syncthreads();
    if (t < NB) {
        gPM[b*NB + t] = binM[t];
        gPD[b*NB + t] = binD[t];
    }
}

// Per-image: reduce partials -> bin means -> NaN-propagating min/max ->
// weights -> weighted sum -> atomic into d_out. (Numerics validated R1/R2.)
__global__ __launch_bounds__(512) void k_final(const float* __restrict__ gPM,
                                               const float* __restrict__ gPD,
                                               const int* __restrict__ counts,
                                               float* __restrict__ out) {
    __shared__ float meanb[NB];
    __shared__ float dsum[NB];
    __shared__ float rmin[512], rmax[512];
    __shared__ double sred[512];
    int t = threadIdx.x, img = blockIdx.x;
    for (int j = t; j < NB; j += 512) {
        float sm = 0.f, sd = 0.f;
        for (int g = 0; g < NCG; ++g) {
            sm += gPM[(size_t)((img << 5) + g)*NB + j];
            sd += gPD[(size_t)((img << 5) + g)*NB + j];
        }
        meanb[j] = sm / (float)counts[j];
        dsum[j] = sd;
    }
    __syncthreads();
    float vmin = INFINITY, vmax = -INFINITY;
    if (t >= 1 && t <= 360) { vmin = meanb[t]; vmax = meanb[t]; }
    rmin[t] = vmin; rmax[t] = vmax;
    __syncthreads();
    for (int s = 256; s > 0; s >>= 1) {
        if (t < s) {
            float a = rmin[t], bb = rmin[t+s];
            rmin[t] = (a != a || bb != bb) ? __int_as_float(0x7fc00000) : fminf(a, bb);
            a = rmax[t]; bb = rmax[t+s];
            rmax[t] = (a != a || bb != bb) ? __int_as_float(0x7fc00000) : fmaxf(a, bb);
        }
        __syncthreads();
    }
    float pmin = rmin[0], pmax = rmax[0];
    double part = 0.0;
    for (int k = t; k < NB; k += 512) {
        float wgt;
        if (k == NB - 1) {
            wgt = 1.0f;
        } else {
            int idx = (k == 0) ? 1 : k;
            float e = (meanb[idx] - pmin) / (pmax - pmin);
            float wv = 1.0f - e;
            if (wv != wv) wv = 0.0f;
            wv = fminf(fmaxf(wv, 0.0f), 1.0f);
            wgt = wv;
        }
        part += (double)wgt * (double)dsum[k];
    }
    sred[t] = part;
    __syncthreads();
    for (int s = 256; s > 0; s >>= 1) {
        if (t < s) sred[t] += sred[t+s];
        __syncthreads();
    }
    if (t == 0) atomicAdd(out, (float)(sred[0] / 6291456.0));
}

extern "C" void kernel_launch(void* const* d_in, const int* in_sizes, int n_in,
                              void* d_out, int out_size, void* d_ws, size_t ws_size,
                              hipStream_t stream) {
    const float* pred = (const float*)d_in[0];
    const float* tgt  = (const float*)d_in[1];
    float* ws = (float*)d_ws;
    hipMemsetAsync((char*)d_ws + (size_t)OFF_CNT*4, 0, NB*4, stream);
    hipMemsetAsync(d_out, 0, sizeof(float), stream);
    k_counts<<<64, 256, 0, stream>>>((int*)(ws + OFF_CNT));
    k_rowfft<<<48*32, 1024, 0, stream>>>(pred, tgt, ws);
    k_colfft<<<NIMG*NCG, 1024, 0, stream>>>(ws, ws + OFF_PM, ws + OFF_PD);
    k_final<<<NIMG, 512, 0, stream>>>(ws + OFF_PM, ws + OFF_PD,
                                      (const int*)(ws + OFF_CNT), (float*)d_out);
}